// Round 1
// baseline (126.189 us; speedup 1.0000x reference)
//
#include <hip/hip_runtime.h>

// Problem constants
#define HW      1024   // H*W = 32*32 = channels of the BN
#define BC      4096   // B*C = 16*256 = elements per BN channel
#define NLAYERS 30

// ---------------------------------------------------------------------------
// K1/K3: tiled transpose of an R x C fp32 matrix (dst is C x R).
// 32x32 tile, block (32,8), 4 rows per thread; LDS padded to kill conflicts.
// ---------------------------------------------------------------------------
__global__ __launch_bounds__(256) void transpose_k(const float* __restrict__ src,
                                                   float* __restrict__ dst,
                                                   int R, int C) {
    __shared__ float tile[32][33];
    const int cb = blockIdx.x * 32;
    const int rb = blockIdx.y * 32;
    const int tx = threadIdx.x;  // 0..31
    const int ty = threadIdx.y;  // 0..7
#pragma unroll
    for (int k = 0; k < 32; k += 8)
        tile[ty + k][tx] = src[(size_t)(rb + ty + k) * C + (cb + tx)];
    __syncthreads();
#pragma unroll
    for (int k = 0; k < 32; k += 8)
        dst[(size_t)(cb + ty + k) * R + (rb + tx)] = tile[tx][ty + k];
}

// ---------------------------------------------------------------------------
// K2: the 30-layer ODE. One block per channel p. 256 threads x 16 values
// (registers) = the 4096 (b,c) values of that channel. Per layer:
//   z = fma(m[c], x1, y);  block-reduce (sum, sumsq);  BN+ReLU6;  Euler step.
// Reduction: 6-step wave butterfly + 4-wave combine through tiny LDS
// (double-buffered so only ONE __syncthreads per layer).
// ---------------------------------------------------------------------------
__global__ __launch_bounds__(256) void ode_main(const float* __restrict__ xT,
                                                const float* __restrict__ delta_t,
                                                const float* __restrict__ matrices,
                                                const float* __restrict__ gamma,
                                                const float* __restrict__ beta,
                                                float* __restrict__ yT) {
    const int p = blockIdx.x;       // channel (spatial position)
    const int t = threadIdx.x;      // 0..255
    const float* xrow = xT + (size_t)p * BC;

    // element index e(j,i) = j*1024 + 4t + i ; (b,c) row r = e ; c = e % 256.
    // Since 1024 % 256 == 0, all 4 j-groups share m[(4t+i) & 255].
    float x1[16], y[16];
#pragma unroll
    for (int j = 0; j < 4; ++j) {
        const float4 v = *(const float4*)(xrow + j * 1024 + 4 * t);
        x1[j * 4 + 0] = v.x; x1[j * 4 + 1] = v.y;
        x1[j * 4 + 2] = v.z; x1[j * 4 + 3] = v.w;
    }
#pragma unroll
    for (int k = 0; k < 16; ++k) y[k] = x1[k];

    const float gp = gamma[p];
    const float bp = beta[p];
    const int   wid  = t >> 6;
    const int   lane = t & 63;
    const int   moff = (4 * t) & 255;

    __shared__ float red[2][8];     // [parity][wave*2 + {sum,sumsq}]

    for (int l = 0; l < NLAYERS; ++l) {
        const float4 mv = *(const float4*)(matrices + l * 256 + moff);
        const float mm[4] = {mv.x, mv.y, mv.z, mv.w};
        const float dtl = fminf(fmaxf(delta_t[l], 0.0f), 6.0f);  // relu6(dt)

        float z[16];
        float s = 0.0f, s2 = 0.0f;
#pragma unroll
        for (int j = 0; j < 4; ++j) {
#pragma unroll
            for (int i = 0; i < 4; ++i) {
                const float zz = fmaf(mm[i], x1[j * 4 + i], y[j * 4 + i]);
                z[j * 4 + i] = zz;
                s  += zz;
                s2  = fmaf(zz, zz, s2);
            }
        }
        // 64-lane butterfly reduction
#pragma unroll
        for (int mask = 1; mask < 64; mask <<= 1) {
            s  += __shfl_xor(s,  mask, 64);
            s2 += __shfl_xor(s2, mask, 64);
        }
        const int par = l & 1;
        if (lane == 0) { red[par][wid * 2] = s; red[par][wid * 2 + 1] = s2; }
        __syncthreads();
        const float S  = red[par][0] + red[par][2] + red[par][4] + red[par][6];
        const float S2 = red[par][1] + red[par][3] + red[par][5] + red[par][7];

        const float mean = S * (1.0f / 4096.0f);
        const float var  = fmaf(-mean, mean, S2 * (1.0f / 4096.0f));
        const float rstd = rsqrtf(var + 1e-5f);
        const float g    = gp * rstd;            // fold gamma into scale
        const float bb   = fmaf(-mean, g, bp);   // fold mean into bias
        const float omdt = 1.0f - dtl;
#pragma unroll
        for (int k = 0; k < 16; ++k) {
            float a = fmaf(z[k], g, bb);
            a = fminf(fmaxf(a, 0.0f), 6.0f);
            y[k] = fmaf(dtl, a, omdt * y[k]);    // y += dt*(-y + a)
        }
    }

    float* yrow = yT + (size_t)p * BC;
#pragma unroll
    for (int j = 0; j < 4; ++j) {
        float4 w;
        w.x = y[j * 4 + 0] + x1[j * 4 + 0];
        w.y = y[j * 4 + 1] + x1[j * 4 + 1];
        w.z = y[j * 4 + 2] + x1[j * 4 + 2];
        w.w = y[j * 4 + 3] + x1[j * 4 + 3];
        *(float4*)(yrow + j * 1024 + 4 * t) = w;
    }
}

// ---------------------------------------------------------------------------
// Launch: K1 x -> xT (scratch = d_out, fully overwritten later by K3),
//         K2 30-layer ODE on xT -> yT (scratch = d_ws, needs 16 MB),
//         K3 yT -> d_out (final layout == x layout).
// ---------------------------------------------------------------------------
extern "C" void kernel_launch(void* const* d_in, const int* in_sizes, int n_in,
                              void* d_out, int out_size, void* d_ws, size_t ws_size,
                              hipStream_t stream) {
    const float* x        = (const float*)d_in[0];   // [16,256,32,32]
    const float* delta_t  = (const float*)d_in[1];   // [30,1]
    const float* matrices = (const float*)d_in[2];   // [30,1,1,16,16]
    const float* gamma    = (const float*)d_in[3];   // [1024]
    const float* beta     = (const float*)d_in[4];   // [1024]
    float* out = (float*)d_out;

    float* xT = out;            // 16 MB scratch; overwritten by K3 at the end
    float* yT = (float*)d_ws;   // 16 MB scratch

    dim3 blk(32, 8);
    // x viewed as [BC=4096][HW=1024] -> xT [1024][4096]
    transpose_k<<<dim3(HW / 32, BC / 32), blk, 0, stream>>>(x, xT, BC, HW);
    ode_main<<<dim3(HW), dim3(256), 0, stream>>>(xT, delta_t, matrices, gamma, beta, yT);
    // yT [1024][4096] -> out [4096][1024]
    transpose_k<<<dim3(BC / 32, HW / 32), blk, 0, stream>>>(yT, out, HW, BC);
}